// Round 7
// baseline (706.831 us; speedup 1.0000x reference)
//
#include <hip/hip_runtime.h>
#include <math.h>

// ---------------- geometry ----------------
#define TPB   256
#define GRID  1024            // 4 blocks/CU x 256 CU -> all co-resident
#define SBLK  256             // blocks 0..255 also compute GMM stats

// ---------------- workspace layout (float indices) ----------------
// [0,16)    : 3 barrier counters (uint) -- memset to 0 each launch
// WS_RED    : [1024] per-block recon partials
// WS_EN     : [1024] per-block energy partials
// WS_MU     : [8][8], WS_CINV: [8][64], WS_COEF/WS_CD: [8]
// WS_STATP  : [360][256] TRANSPOSED stat partials (slot-major)
#define WS_RED   64
#define WS_EN    1088
#define WS_MU    2112
#define WS_CINV  2176
#define WS_COEF  2688
#define WS_CD    2696
#define WS_STATP 4096

static constexpr int NSAMP = 262144;      // B*T*C
static constexpr int NX4   = 4194304;     // x float4 count
static constexpr float EPSF = 1e-12f;

__device__ inline float wave_reduce_sum(float v) {
    #pragma unroll
    for (int m = 1; m < 64; m <<= 1) v += __shfl_xor(v, m, 64);
    return v;
}
__device__ inline double wave_reduce_sum_d(double v) {
    #pragma unroll
    for (int m = 1; m < 64; m <<= 1) v += __shfl_xor(v, m, 64);
    return v;
}

// device-scope grid barrier: counters pre-zeroed by host-side memsetAsync.
__device__ inline void grid_barrier(unsigned* cnt, unsigned target) {
    __syncthreads();
    if (threadIdx.x == 0) {
        __threadfence();                       // release our global writes
        atomicAdd(cnt, 1u);                    // device-scope arrive
        while (__hip_atomic_load(cnt, __ATOMIC_ACQUIRE,
                                 __HIP_MEMORY_SCOPE_AGENT) < target)
            __builtin_amdgcn_s_sleep(8);
        __threadfence();                       // acquire remote writes
    }
    __syncthreads();
}

__global__ __launch_bounds__(TPB, 4) void kmega(const float4* __restrict__ x,
                                                const float4* __restrict__ xh,
                                                const float4* __restrict__ z4,
                                                const float* __restrict__ gamma,
                                                float* __restrict__ ws,
                                                float* __restrict__ out) {
    __shared__ float  sred[4];
    __shared__ float  slds[4][360];
    __shared__ double sstat[360];
    __shared__ double schol[8][192];          // per k: A[64] | L[64] | M[64]
    __shared__ float  smu[64], scinv[512], scoef[8];
    __shared__ double dred[4], dren[4];

    unsigned* cnt = (unsigned*)ws;
    const int b = blockIdx.x, tid = threadIdx.x;

    // ================= Phase A: recon slice (all blocks) =================
    float racc = 0.f;
    if (b < SBLK) {
        const int base = b * 1024 + tid;          // 4 float4-pairs
        float4 xa[4], xb[4];
        #pragma unroll
        for (int i = 0; i < 4; ++i) xa[i] = x[base + i * 256];
        #pragma unroll
        for (int i = 0; i < 4; ++i) xb[i] = xh[base + i * 256];
        #pragma unroll
        for (int i = 0; i < 4; ++i) {
            float d0 = xb[i].x - xa[i].x, d1 = xb[i].y - xa[i].y;
            float d2 = xb[i].z - xa[i].z, d3 = xb[i].w - xa[i].w;
            racc = fmaf(d0, d0, racc); racc = fmaf(d1, d1, racc);
            racc = fmaf(d2, d2, racc); racc = fmaf(d3, d3, racc);
        }
    } else {
        const int base = SBLK * 1024 + (b - SBLK) * 5120 + tid;  // 20 pairs
        #pragma unroll 1
        for (int bt = 0; bt < 5; ++bt) {
            float4 xa[4], xb[4];
            #pragma unroll
            for (int i = 0; i < 4; ++i) xa[i] = x[base + (bt * 4 + i) * 256];
            #pragma unroll
            for (int i = 0; i < 4; ++i) xb[i] = xh[base + (bt * 4 + i) * 256];
            #pragma unroll
            for (int i = 0; i < 4; ++i) {
                float d0 = xb[i].x - xa[i].x, d1 = xb[i].y - xa[i].y;
                float d2 = xb[i].z - xa[i].z, d3 = xb[i].w - xa[i].w;
                racc = fmaf(d0, d0, racc); racc = fmaf(d1, d1, racc);
                racc = fmaf(d2, d2, racc); racc = fmaf(d3, d3, racc);
            }
        }
    }
    {
        float v = wave_reduce_sum(racc);
        int w = tid >> 6;
        if ((tid & 63) == 0) sred[w] = v;
        __syncthreads();
        if (tid == 0) ws[WS_RED + b] = sred[0] + sred[1] + sred[2] + sred[3];
    }

    // ================= Phase A2: GMM stats (blocks 0..SBLK) =================
    if (b < SBLK) {
        float acc[45];
        #pragma unroll
        for (int i = 0; i < 45; ++i) acc[i] = 0.f;
        const int k = tid & 7;
        const int sg = tid >> 3;                  // 0..31
        // block covers samples [b*1024, (b+1)*1024): 32 iters of 32 samples
        for (int it = 0; it < 32; it += 4) {
            float4 za[4], zb[4]; float gg[4];
            #pragma unroll
            for (int u = 0; u < 4; ++u) {
                int n = b * 1024 + (it + u) * 32 + sg;
                za[u] = z4[n * 2]; zb[u] = z4[n * 2 + 1];
                gg[u] = gamma[n * 8 + k];
            }
            #pragma unroll
            for (int u = 0; u < 4; ++u) {
                float zv[8] = {za[u].x, za[u].y, za[u].z, za[u].w,
                               zb[u].x, zb[u].y, zb[u].z, zb[u].w};
                float g = gg[u];
                acc[0] += g;
                float gz[8];
                #pragma unroll
                for (int i = 0; i < 8; ++i) { gz[i] = g * zv[i]; acc[1 + i] += gz[i]; }
                #pragma unroll
                for (int i = 0; i < 8; ++i) {
                    #pragma unroll
                    for (int j = 0; j < 8; ++j) {
                        if (j <= i)
                            acc[9 + (i * (i + 1)) / 2 + j] =
                                fmaf(gz[i], zv[j], acc[9 + (i * (i + 1)) / 2 + j]);
                    }
                }
            }
        }
        #pragma unroll
        for (int i = 0; i < 45; ++i) {
            float v = acc[i];
            v += __shfl_xor(v, 8, 64);
            v += __shfl_xor(v, 16, 64);
            v += __shfl_xor(v, 32, 64);
            acc[i] = v;
        }
        int lane = tid & 63, w = tid >> 6;
        if (lane < 8) {
            #pragma unroll
            for (int i = 0; i < 45; ++i) slds[w][lane * 45 + i] = acc[i];
        }
        __syncthreads();
        for (int v = tid; v < 360; v += TPB)
            ws[WS_STATP + v * 256 + b] =                     // transposed
                slds[0][v] + slds[1][v] + slds[2][v] + slds[3][v];
    }

    grid_barrier(cnt + 0, GRID);

    // ================= Phase C: finalize (block 0 only) =================
    if (b == 0) {
        for (int v = tid; v < 360; v += TPB) {
            const float4* p = (const float4*)&ws[WS_STATP + v * 256];
            double s0 = 0, s1 = 0, s2 = 0, s3 = 0;
            #pragma unroll 4
            for (int q = 0; q < 64; q += 4) {
                float4 a0 = p[q], a1 = p[q + 1], a2 = p[q + 2], a3 = p[q + 3];
                s0 += (double)a0.x + (double)a0.y + (double)a0.z + (double)a0.w;
                s1 += (double)a1.x + (double)a1.y + (double)a1.z + (double)a1.w;
                s2 += (double)a2.x + (double)a2.y + (double)a2.z + (double)a2.w;
                s3 += (double)a3.x + (double)a3.y + (double)a3.z + (double)a3.w;
            }
            sstat[v] = (s0 + s1) + (s2 + s3);
        }
        __syncthreads();
        if (tid < 8) {
            const int k = tid;
            double* A = &schol[k][0];
            double* L = &schol[k][64];
            double* M = &schol[k][128];
            const double* st = &sstat[k * 45];
            double g = st[0];
            double mu[8];
            for (int d = 0; d < 8; ++d) mu[d] = st[1 + d] / g;
            {
                int t = 0;
                for (int i = 0; i < 8; ++i)
                    for (int j = 0; j <= i; ++j) {
                        double v = st[9 + t] / g - mu[i] * mu[j];
                        A[i * 8 + j] = v; A[j * 8 + i] = v; ++t;
                    }
            }
            for (int d = 0; d < 8; ++d) A[d * 8 + d] += (double)EPSF;

            double cd = 0.0;
            for (int d = 0; d < 8; ++d) cd += 1.0 / A[d * 8 + d];
            ws[WS_CD + k] = (float)cd;

            for (int i = 0; i < 8; ++i)
                for (int j = 0; j <= i; ++j) {
                    double s = A[i * 8 + j];
                    for (int p = 0; p < j; ++p) s -= L[i * 8 + p] * L[j * 8 + p];
                    if (i == j) L[i * 8 + i] = sqrt(s);
                    else        L[i * 8 + j] = s / L[j * 8 + j];
                }
            for (int i = 0; i < 8; ++i) {
                M[i * 8 + i] = 1.0 / L[i * 8 + i];
                for (int j = 0; j < i; ++j) {
                    double s = 0.0;
                    for (int p = j; p < i; ++p) s -= L[i * 8 + p] * M[p * 8 + j];
                    M[i * 8 + j] = s / L[i * 8 + i];
                }
            }
            for (int i = 0; i < 8; ++i)
                for (int j = 0; j < 8; ++j) {
                    double s = 0.0;
                    int p0 = i > j ? i : j;
                    for (int p = p0; p < 8; ++p) s += M[p * 8 + i] * M[p * 8 + j];
                    ws[WS_CINV + k * 64 + i * 8 + j] = (float)s;
                }
            // det_cov = (2pi)^4 * prod diag(L); reference divides by sqrt(det_cov)
            double det = 1.0;
            for (int d = 0; d < 8; ++d) det *= L[d * 8 + d];
            double c = 2.0 * M_PI;
            det *= c * c * c * c;
            ws[WS_COEF + k] = (float)((g / (double)NSAMP) / sqrt(det));
            for (int d = 0; d < 8; ++d) ws[WS_MU + k * 8 + d] = (float)mu[d];
        }
    }

    grid_barrier(cnt + 1, GRID);

    // ================= Phase D: sample energy (all blocks) =================
    for (int i = tid; i < 64;  i += TPB) smu[i]   = ws[WS_MU + i];
    for (int i = tid; i < 512; i += TPB) scinv[i] = ws[WS_CINV + i];
    if (tid < 8) scoef[tid] = ws[WS_COEF + tid];
    __syncthreads();

    {
        const int n = b * 256 + tid;              // exact cover of NSAMP
        float4 a = z4[n * 2], bb = z4[n * 2 + 1];
        float zv[8] = {a.x, a.y, a.z, a.w, bb.x, bb.y, bb.z, bb.w};
        float sacc = 0.f;
        #pragma unroll 1
        for (int k = 0; k < 8; ++k) {
            float dv[8];
            #pragma unroll
            for (int i = 0; i < 8; ++i) dv[i] = zv[i] - smu[k * 8 + i];
            float quad = 0.f;
            #pragma unroll
            for (int i = 0; i < 8; ++i) {
                float4 c0 = *(const float4*)&scinv[k * 64 + i * 8];
                float4 c1 = *(const float4*)&scinv[k * 64 + i * 8 + 4];
                float r;
                r = c0.x * dv[0];
                r = fmaf(c0.y, dv[1], r);
                r = fmaf(c0.z, dv[2], r);
                r = fmaf(c0.w, dv[3], r);
                r = fmaf(c1.x, dv[4], r);
                r = fmaf(c1.y, dv[5], r);
                r = fmaf(c1.z, dv[6], r);
                r = fmaf(c1.w, dv[7], r);
                quad = fmaf(dv[i], r, quad);
            }
            sacc = fmaf(scoef[k], __expf(-0.5f * quad), sacc);
        }
        float e = -__logf(sacc + EPSF);
        float v = wave_reduce_sum(e);
        __syncthreads();                          // sred reuse
        int w = tid >> 6;
        if ((tid & 63) == 0) sred[w] = v;
        __syncthreads();
        if (tid == 0) ws[WS_EN + b] = sred[0] + sred[1] + sred[2] + sred[3];
    }

    grid_barrier(cnt + 2, GRID);

    // ================= Phase E: final combine (block 0) =================
    if (b == 0) {
        double accR = 0.0, accE = 0.0;
        #pragma unroll 4
        for (int i = tid; i < GRID; i += TPB) accR += (double)ws[WS_RED + i];
        #pragma unroll 4
        for (int i = tid; i < GRID; i += TPB) accE += (double)ws[WS_EN + i];
        accR = wave_reduce_sum_d(accR);
        accE = wave_reduce_sum_d(accE);
        int w = tid >> 6;
        if ((tid & 63) == 0) { dred[w] = accR; dren[w] = accE; }
        __syncthreads();
        if (tid == 0) {
            double R = dred[0] + dred[1] + dred[2] + dred[3];
            double E = dren[0] + dren[1] + dren[2] + dren[3];
            double cd = 0.0;
            for (int k = 0; k < 8; ++k) cd += (double)ws[WS_CD + k];
            out[0] = (float)(R / ((double)NSAMP * 64.0)
                           + 0.1 * (E / (double)NSAMP)
                           + 0.005 * cd);
        }
    }
}

extern "C" void kernel_launch(void* const* d_in, const int* in_sizes, int n_in,
                              void* d_out, int out_size, void* d_ws, size_t ws_size,
                              hipStream_t stream) {
    const float* x     = (const float*)d_in[0];
    const float* xh    = (const float*)d_in[1];
    const float* z     = (const float*)d_in[2];
    const float* gamma = (const float*)d_in[3];
    float* ws = (float*)d_ws;

    hipMemsetAsync(ws, 0, 64, stream);            // zero barrier counters
    kmega<<<GRID, TPB, 0, stream>>>((const float4*)x, (const float4*)xh,
                                    (const float4*)z, gamma, ws, (float*)d_out);
}